// Round 9
// baseline (74.423 us; speedup 1.0000x reference)
//
#include <hip/hip_runtime.h>

// Sinkhorn (L1 cost), n=2048, d=64, eps=100, 10 frozen-on-converge iters.
// Scaling form; K and K^T in FP16 (8 MiB each, XCD-pinned slices, L2-resident).
// Transpose fused into build via LDS reuse (34KB -> 4 blocks/CU). Early-exit
// once converged. 23 dispatches: build + 10x(rowz,colw) + loss + reduce.
// Launch = cheapest global barrier (r2: grid.sync ~25us; r3: atomic chain
// ~100ns/block). No atomics, no coop sync, no tiny-grid latency reducers.

#define N 2048
#define EPS 100.0f
#define INV_EPS 0.01f
#define LOG_MU (-7.6246189861593985f)   // log(1/2048)
#define MU (4.8828125e-4f)              // 1/2048 exact
#define NITER 10
#define TOL 0.1f

typedef _Float16 h16x8 __attribute__((ext_vector_type(8)));
typedef _Float16 h16x4 __attribute__((ext_vector_type(4)));

__device__ __forceinline__ float wave_sum(float s) {
  #pragma unroll
  for (int off = 32; off > 0; off >>= 1) s += __shfl_down(s, off, 64);
  return s;
}

// ---------------- build: K = exp(-L1/eps) fp16, KT fused, init state ----------------
// 1024 blocks, K XCD-row-pinned: g=b&7 -> i-rows [g*256, g*256+256).
// LDS: As reused as transpose-staging after the compute loop -> 34 KB, 4 blk/CU.
__global__ __launch_bounds__(256) void build_k(const float* __restrict__ A,
                                               const float* __restrict__ B,
                                               _Float16* __restrict__ K,
                                               _Float16* __restrict__ KT,
                                               float* __restrict__ z_hist,
                                               float* __restrict__ w_hist,
                                               float* __restrict__ u_hist,
                                               int* __restrict__ idx_arr,
                                               int* __restrict__ done_arr) {
  __shared__ float As[64][68];   // inputs transposed [k][i]; later: K-tile staging
  __shared__ float Bs[64][68];
  const int b = blockIdx.x;
  const int g = b & 7, t = b >> 3;
  const int itl = t >> 5, jt = t & 31;
  const int i0 = (g * 4 + itl) * 64, j0 = jt * 64;
  const int tid = threadIdx.x;
  if (b == 0) {   // init hist slot 0 + chain scalars
    #pragma unroll
    for (int q = 0; q < 8; ++q) {
      int r = q * 256 + tid;
      z_hist[r] = 1.f; w_hist[r] = 1.f; u_hist[r] = 0.f;
    }
    if (tid == 0) { idx_arr[0] = 0; done_arr[0] = 0; }
  }
  #pragma unroll
  for (int e = 0; e < 16; ++e) {
    int idx = e * 256 + tid;
    int r = idx >> 6, k = idx & 63;
    As[k][r] = A[(i0 + r) * 64 + k];
    Bs[k][r] = B[(j0 + r) * 64 + k];
  }
  __syncthreads();
  const int ty = tid >> 4, tx = tid & 15;
  float acc[4][4] = {};
  #pragma unroll 8
  for (int k = 0; k < 64; ++k) {
    float4 av = *(const float4*)&As[k][ty * 4];
    float4 bv = *(const float4*)&Bs[k][tx * 4];
    float a[4] = {av.x, av.y, av.z, av.w};
    float c[4] = {bv.x, bv.y, bv.z, bv.w};
    #pragma unroll
    for (int p = 0; p < 4; ++p)
      #pragma unroll
      for (int q = 0; q < 4; ++q)
        acc[p][q] += fabsf(a[p] - c[q]);   // sub + add-with-abs-modifier
  }
  __syncthreads();   // all As reads done; safe to reuse As as staging
  float (*T)[68] = As;
  #pragma unroll
  for (int p = 0; p < 4; ++p) {
    float4 e4 = make_float4(__expf(-acc[p][0] * INV_EPS), __expf(-acc[p][1] * INV_EPS),
                            __expf(-acc[p][2] * INV_EPS), __expf(-acc[p][3] * INV_EPS));
    h16x4 kv;
    kv[0] = (_Float16)e4.x; kv[1] = (_Float16)e4.y;
    kv[2] = (_Float16)e4.z; kv[3] = (_Float16)e4.w;
    *(h16x4*)&K[(size_t)(i0 + ty * 4 + p) * N + j0 + tx * 4] = kv;
    T[ty * 4 + p][tx * 4 + 0] = e4.x;
    T[ty * 4 + p][tx * 4 + 1] = e4.y;
    T[ty * 4 + p][tx * 4 + 2] = e4.z;
    T[ty * 4 + p][tx * 4 + 3] = e4.w;
  }
  __syncthreads();
  // KT write: thread (ty,tx) -> KT rows j0+ty*4+p, cols i0+tx*4 (coalesced 8B)
  #pragma unroll
  for (int p = 0; p < 4; ++p) {
    int jl = ty * 4 + p;
    h16x4 o;
    o[0] = (_Float16)T[tx * 4 + 0][jl]; o[1] = (_Float16)T[tx * 4 + 1][jl];
    o[2] = (_Float16)T[tx * 4 + 2][jl]; o[3] = (_Float16)T[tx * 4 + 3][jl];
    *(h16x4*)&KT[(size_t)(j0 + jl) * N + i0 + tx * 4] = o;
  }
}

// ---------------- row matvec: z' and u_new (skipped once converged) ----------------
// 256 blocks x 512 thr; wave wv (0..7) owns row rbase+wv (XCD-local K rows)
__global__ __launch_bounds__(512) void rowz(const _Float16* __restrict__ K,
    float* __restrict__ z_hist, const float* __restrict__ w_hist,
    float* __restrict__ u_hist, const int* __restrict__ idx_arr,
    const int* __restrict__ done_arr, int it) {
  if (done_arr[it]) return;       // slot it+1 never referenced by idx chain
  __shared__ float wl[N];
  const int tid = threadIdx.x, wv = tid >> 6, lane = tid & 63;
  const int b = blockIdx.x;
  const int rbase = ((b & 7) << 8) + ((b >> 3) << 3);
  const int idx = idx_arr[it];
  *(float4*)&wl[tid * 4] = *(const float4*)(w_hist + (size_t)idx * N + tid * 4);
  __syncthreads();
  const int r = rbase + wv;
  const _Float16* __restrict__ Krow = K + (size_t)r * N;
  float s = 0.f;
  #pragma unroll
  for (int p = 0; p < 4; ++p) {
    int j = lane * 8 + p * 512;          // wave covers contiguous 1 KB per step
    h16x8 k8 = *(const h16x8*)(Krow + j);
    float4 wa = *(const float4*)&wl[j];
    float4 wb = *(const float4*)&wl[j + 4];
    s += (float)k8[0] * wa.x + (float)k8[1] * wa.y
       + (float)k8[2] * wa.z + (float)k8[3] * wa.w
       + (float)k8[4] * wb.x + (float)k8[5] * wb.y
       + (float)k8[6] * wb.z + (float)k8[7] * wb.w;
  }
  s = wave_sum(s);
  if (lane == 0) {
    float zc = z_hist[(size_t)idx * N + r];
    float den = zc * s + 1e-6f;          // == rowsum(exp(M)) + 1e-6 of reference
    z_hist[(size_t)(it + 1) * N + r] = zc * MU / den;
    u_hist[(size_t)(it + 1) * N + r] =
        EPS * (LOG_MU - logf(den)) + u_hist[(size_t)idx * N + r];
  }
}

// ---------------- col matvec: w'; block 0 runs err/done/idx chain ----------------
// 256 blocks x 512 thr; wave wv owns column jbase+wv (XCD-local KT rows)
__global__ __launch_bounds__(512) void colw(const _Float16* __restrict__ KT,
    const float* __restrict__ z_hist, float* __restrict__ w_hist,
    const float* __restrict__ u_hist, int* __restrict__ idx_arr,
    int* __restrict__ done_arr, int it) {
  const int tid = threadIdx.x, wv = tid >> 6, lane = tid & 63;
  const int b = blockIdx.x;
  const int dprev = done_arr[it];
  if (dprev) {                    // frozen: just propagate the chain
    if (b == 0 && tid == 0) { idx_arr[it + 1] = idx_arr[it]; done_arr[it + 1] = 1; }
    return;
  }
  __shared__ float zl[N];
  const int jbase = ((b & 7) << 8) + ((b >> 3) << 3);
  const int idx = idx_arr[it];
  *(float4*)&zl[tid * 4] = *(const float4*)(z_hist + (size_t)(it + 1) * N + tid * 4);
  __syncthreads();
  const int j = jbase + wv;
  const _Float16* __restrict__ Kc = KT + (size_t)j * N;
  float s = 0.f;
  #pragma unroll
  for (int p = 0; p < 4; ++p) {
    int i = lane * 8 + p * 512;
    h16x8 k8 = *(const h16x8*)(Kc + i);
    float4 za = *(const float4*)&zl[i];
    float4 zb = *(const float4*)&zl[i + 4];
    s += (float)k8[0] * za.x + (float)k8[1] * za.y
       + (float)k8[2] * za.z + (float)k8[3] * za.w
       + (float)k8[4] * zb.x + (float)k8[5] * zb.y
       + (float)k8[6] * zb.z + (float)k8[7] * zb.w;
  }
  s = wave_sum(s);
  if (lane == 0) {
    float wc = w_hist[(size_t)idx * N + j];
    float den = wc * s + 1e-6f;
    w_hist[(size_t)(it + 1) * N + j] = wc * MU / den;
  }
  if (b == 0) {   // block-uniform branch: err in u-domain + convergence chain
    const float* __restrict__ un = u_hist + (size_t)(it + 1) * N;
    const float* __restrict__ uc = u_hist + (size_t)idx * N;
    float4 a = *(const float4*)(un + tid * 4);
    float4 c = *(const float4*)(uc + tid * 4);
    float e = fabsf(a.x - c.x) + fabsf(a.y - c.y)
            + fabsf(a.z - c.z) + fabsf(a.w - c.w);
    e = wave_sum(e);
    __shared__ float sh8[8];
    if (lane == 0) sh8[wv] = e;
    __syncthreads();
    if (tid == 0) {
      float err = ((sh8[0] + sh8[1]) + (sh8[2] + sh8[3]))
                + ((sh8[4] + sh8[5]) + (sh8[6] + sh8[7]));
      idx_arr[it + 1] = it + 1;
      done_arr[it + 1] = (err < TOL) ? 1 : 0;
    }
  }
}

// ---------------- loss: sum_i z_i sum_j K_ij * w_j * (-eps*log(K_ij)) ----------------
__global__ __launch_bounds__(512) void loss_pass(const _Float16* __restrict__ K,
    const float* __restrict__ z_hist, const float* __restrict__ w_hist,
    const int* __restrict__ idx_arr, float* __restrict__ losspart) {
  __shared__ float wl[N];
  __shared__ float sh8[8];
  const int tid = threadIdx.x, wv = tid >> 6, lane = tid & 63;
  const int b = blockIdx.x;
  const int rbase = ((b & 7) << 8) + ((b >> 3) << 3);
  const int idx = idx_arr[NITER];
  *(float4*)&wl[tid * 4] = *(const float4*)(w_hist + (size_t)idx * N + tid * 4);
  __syncthreads();
  const int r = rbase + wv;
  const _Float16* __restrict__ Krow = K + (size_t)r * N;
  float s = 0.f;
  #pragma unroll
  for (int p = 0; p < 4; ++p) {
    int j = lane * 8 + p * 512;
    h16x8 k8 = *(const h16x8*)(Krow + j);
    #pragma unroll
    for (int q = 0; q < 8; ++q) {
      float kf = (float)k8[q];
      s += kf * wl[j + q] * (-EPS * __logf(kf));
    }
  }
  s = wave_sum(s);
  if (lane == 0) sh8[wv] = s * z_hist[(size_t)idx * N + r];
  __syncthreads();
  if (tid == 0)
    losspart[b] = ((sh8[0] + sh8[1]) + (sh8[2] + sh8[3]))
                + ((sh8[4] + sh8[5]) + (sh8[6] + sh8[7]));
}

__global__ __launch_bounds__(256) void loss_reduce(const float* __restrict__ losspart,
                                                   float* __restrict__ out) {
  float s = losspart[threadIdx.x];
  s = wave_sum(s);
  __shared__ float sh4[4];
  if ((threadIdx.x & 63) == 0) sh4[threadIdx.x >> 6] = s;
  __syncthreads();
  if (threadIdx.x == 0) out[0] = (sh4[0] + sh4[1]) + (sh4[2] + sh4[3]);
}

extern "C" void kernel_launch(void* const* d_in, const int* in_sizes, int n_in,
                              void* d_out, int out_size, void* d_ws, size_t ws_size,
                              hipStream_t stream) {
  const float* A = (const float*)d_in[0];
  const float* B = (const float*)d_in[1];
  float* out = (float*)d_out;

  char* base = (char*)d_ws;
  _Float16* K    = (_Float16*)base;                              // 8 MiB
  _Float16* KT   = (_Float16*)(base + (size_t)N * N * 2);        // 8 MiB
  float* z_hist  = (float*)(base + (size_t)2 * N * N * 2);       // [11][N]
  float* w_hist  = z_hist + (size_t)(NITER + 1) * N;
  float* u_hist  = w_hist + (size_t)(NITER + 1) * N;
  float* losspart= u_hist + (size_t)(NITER + 1) * N;             // [256]
  int*   idx_arr = (int*)(losspart + 256);                       // [11]
  int*   done_arr= idx_arr + (NITER + 1);                        // [11]

  build_k<<<1024, 256, 0, stream>>>(A, B, K, KT, z_hist, w_hist, u_hist,
                                    idx_arr, done_arr);
  for (int it = 0; it < NITER; ++it) {
    rowz<<<256, 512, 0, stream>>>(K, z_hist, w_hist, u_hist, idx_arr,
                                  done_arr, it);
    colw<<<256, 512, 0, stream>>>(KT, z_hist, w_hist, u_hist, idx_arr,
                                  done_arr, it);
  }
  loss_pass<<<256, 512, 0, stream>>>(K, z_hist, w_hist, idx_arr, losspart);
  loss_reduce<<<1, 256, 0, stream>>>(losspart, out);
}